// Round 2
// baseline (803.616 us; speedup 1.0000x reference)
//
#include <hip/hip_runtime.h>
#include <hip/hip_bf16.h>
#include <stdint.h>

// ---------------------------------------------------------------------------
// HyperedgeEmbeddingExtractor: gather -> segment mean -> Linear -> LN -> GELU
// Pipeline:
//   k_zero   : zero begin/end arrays
//   k_bounds : segment boundaries from sorted seg_ids (scatter)
//   k_wsplit : split W fp32 -> bf16 hi/lo, pre-packed in MFMA B-fragment order
//   k_mean   : per-edge gather + mean, bf16 hi/lo split written INTO d_out
//              (row e occupies 2048 B: 512 hi shorts then 512 lo shorts —
//               same footprint as the fp32 output row it becomes later)
//   k_gemm   : bf16x3 MFMA GEMM (AhWh + AlWh + AhWl) fused bias+LN+GELU;
//              reads A from d_out (block-private rows), overwrites with result
// Workspace use: ~2.9 MB (bounds + packed W splits) — safe for any ws_size.
// ---------------------------------------------------------------------------

typedef __attribute__((ext_vector_type(8))) short short8;
typedef __attribute__((ext_vector_type(4))) float f32x4;
typedef __attribute__((ext_vector_type(4))) float float4v;
typedef __attribute__((ext_vector_type(4))) unsigned short u16x4;

__device__ __forceinline__ unsigned short f2bf(float f) {
  __hip_bfloat16 h = __float2bfloat16(f);
  return __builtin_bit_cast(unsigned short, h);
}
__device__ __forceinline__ float bf2f(unsigned short u) {
  __hip_bfloat16 h = __builtin_bit_cast(__hip_bfloat16, u);
  return __bfloat162float(h);
}

// async global->LDS, 16B per lane. dst is wave-uniform base (HW adds lane*16).
__device__ __forceinline__ void gld_lds16(const void* g, void* l) {
  __builtin_amdgcn_global_load_lds(
      (const __attribute__((address_space(1))) uint32_t*)g,
      (__attribute__((address_space(3))) uint32_t*)l, 16, 0, 0);
}

// ---------------------------------------------------------------------------
__global__ void k_zero(int* __restrict__ beg, int* __restrict__ end_, int E) {
  int i = blockIdx.x * 256 + threadIdx.x;
  if (i < E) { beg[i] = 0; end_[i] = 0; }
}

__global__ void k_bounds(const int* __restrict__ seg, int* __restrict__ beg,
                         int* __restrict__ end_, int M) {
  int i = blockIdx.x * 256 + threadIdx.x;
  if (i >= M) return;
  int s = seg[i];
  if (i == 0 || seg[i - 1] != s) beg[s] = i;
  if (i == M - 1 || seg[i + 1] != s) end_[s] = i + 1;
}

// W[512][512] fp32 -> Whi/Wlo packed: [kt(16)][g(4)][c(512)][j(8)], k=32kt+8g+j
__global__ void k_wsplit(const float* __restrict__ W, unsigned short* __restrict__ Whi,
                         unsigned short* __restrict__ Wlo) {
  int t = blockIdx.x * 256 + threadIdx.x;
  if (t >= 512 * 512) return;
  int k = t >> 9, c = t & 511;
  float w = W[t];
  unsigned short hi = f2bf(w);
  unsigned short lo = f2bf(w - bf2f(hi));
  int o = (k >> 3) * 4096 + c * 8 + (k & 7);
  Whi[o] = hi;
  Wlo[o] = lo;
}

// one block (128 threads) per edge: float4 gather-sum, mean, bf16 hi/lo split
// written into a16 (= d_out): row e = [e*1024 .. e*1024+512) hi, +512 lo.
__global__ void k_mean(const float* __restrict__ z, const int* __restrict__ midx,
                       const int* __restrict__ beg, const int* __restrict__ end_,
                       unsigned short* a16) {
  const int e = blockIdx.x;
  const int t = threadIdx.x;  // 0..127, owns 4 consecutive floats
  const int b = beg[e], en = end_[e];
  float4v acc = {0.f, 0.f, 0.f, 0.f};
  for (int m = b; m < en; ++m) {
    const int r = midx[m];
    const float4v v = *(const float4v*)(z + (size_t)r * 512 + t * 4);
    acc.x += v.x; acc.y += v.y; acc.z += v.z; acc.w += v.w;
  }
  const int cnt = en - b;
  const float den = (float)(cnt > 0 ? cnt : 1);
  float m0 = acc.x / den, m1 = acc.y / den, m2 = acc.z / den, m3 = acc.w / den;
  u16x4 hi, lo;
  hi.x = f2bf(m0); lo.x = f2bf(m0 - bf2f(hi.x));
  hi.y = f2bf(m1); lo.y = f2bf(m1 - bf2f(hi.y));
  hi.z = f2bf(m2); lo.z = f2bf(m2 - bf2f(hi.z));
  hi.w = f2bf(m3); lo.w = f2bf(m3 - bf2f(hi.w));
  *(u16x4*)(a16 + (size_t)e * 1024 + t * 4) = hi;
  *(u16x4*)(a16 + (size_t)e * 1024 + 512 + t * 4) = lo;
}

// ---------------------------------------------------------------------------
// GEMM: out[e][c] = GELU(LN(mean[e][:] @ W[:][c] + b[c]))
// block = 256 threads (4 waves), tile 64 rows x 512 cols.
// wave w: cols [128w,128w+128), all 64 rows. acc[4 mf][8 nf] f32x4.
// K' = 3*512 (bf16x3 passes), staged in 48 steps of K=32.
// A is read from a16 (== d_out, block-private rows) and overwritten at the end.
// ---------------------------------------------------------------------------
#define KSTEPS 48

__launch_bounds__(256, 2)
__global__ void k_gemm(const unsigned short* a16,
                       const unsigned short* __restrict__ Whi,
                       const unsigned short* __restrict__ Wlo,
                       const float* __restrict__ bias, const float* __restrict__ gamma,
                       const float* __restrict__ beta, float* out, int E) {
  __shared__ short lA[2][64 * 32];        // 8 KB   [row][k-chunk swizzled]
  __shared__ short lB[2][4 * 512 * 8];    // 64 KB  [g][c][j]
  __shared__ float lRed[64 * 4];          // per-row per-wave partials
  __shared__ float lMu[64], lRs[64];

  const int t = threadIdx.x;
  const int w = t >> 6, l = t & 63;
  const int g = l >> 4, l15 = l & 15;
  const int cw = w * 128;
  const int e0 = blockIdx.x * 64;

  f32x4 acc[4][8];
#pragma unroll
  for (int mf = 0; mf < 4; ++mf)
#pragma unroll
    for (int nf = 0; nf < 8; ++nf) acc[mf][nf] = (f32x4){0.f, 0.f, 0.f, 0.f};

  auto stage = [&](int s) {
    const int p = s >> 4, kt = s & 15, buf = s & 1;
    const int poff = (p == 1) ? 512 : 0;          // Alo lives at +512 shorts
    const unsigned short* Bs = (p == 2) ? Wlo : Whi;
    // A: 64 rows x 32 k (64B/row), one 16B chunk per thread. XOR source-swizzle
    // so readers' strided b128 hits distinct bank-quads per phase.
    {
      const int row = t >> 2, cd = t & 3;
      const int cs = cd ^ ((row >> 1) & 3);
      int rsrc = e0 + row;
      if (rsrc > E - 1) rsrc = E - 1;
      gld_lds16(a16 + (size_t)rsrc * 1024 + poff + kt * 32 + cs * 8,
                &lA[buf][w * 512]);
    }
    // B: 32KB linear copy of pre-packed fragment layout (2048 chunks, 8/thread)
    const unsigned short* gb = Bs + (size_t)kt * 16384;
#pragma unroll
    for (int i = 0; i < 8; ++i) {
      gld_lds16(gb + (size_t)(i * 256 + t) * 8, &lB[buf][(i * 256 + w * 64) * 8]);
    }
  };

  stage(0);
  for (int s = 0; s < KSTEPS; ++s) {
    __syncthreads();                       // stage(s) landed; buffers safe
    if (s + 1 < KSTEPS) stage(s + 1);      // async into other buffer
    const int buf = s & 1;
    short8 af[4];
#pragma unroll
    for (int mf = 0; mf < 4; ++mf) {
      const int R = 16 * mf + l15;
      const int cc = g ^ ((R >> 1) & 3);
      af[mf] = *(const short8*)&lA[buf][R * 32 + cc * 8];
    }
#pragma unroll
    for (int nf = 0; nf < 8; ++nf) {
      const short8 bf = *(const short8*)&lB[buf][(g * 512 + cw + 16 * nf + l15) * 8];
#pragma unroll
      for (int mf = 0; mf < 4; ++mf)
        acc[mf][nf] = __builtin_amdgcn_mfma_f32_16x16x32_bf16(af[mf], bf, acc[mf][nf], 0, 0, 0);
    }
  }
  __syncthreads();

  // ---- epilogue: bias + LayerNorm + GELU (exact erf) ----
  float bia[8], gam[8], bet[8];
#pragma unroll
  for (int nf = 0; nf < 8; ++nf) {
    const int col = cw + 16 * nf + l15;
    bia[nf] = bias[col]; gam[nf] = gamma[col]; bet[nf] = beta[col];
  }
#pragma unroll
  for (int mf = 0; mf < 4; ++mf)
#pragma unroll
    for (int nf = 0; nf < 8; ++nf)
#pragma unroll
      for (int r = 0; r < 4; ++r) acc[mf][nf][r] += bia[nf];

  // mean: in-lane sum over 8 cols, then 16-lane shfl reduce, cross-wave via LDS
  float s_[4][4];
#pragma unroll
  for (int mf = 0; mf < 4; ++mf)
#pragma unroll
    for (int r = 0; r < 4; ++r) {
      float v = 0.f;
#pragma unroll
      for (int nf = 0; nf < 8; ++nf) v += acc[mf][nf][r];
      v += __shfl_xor(v, 1); v += __shfl_xor(v, 2);
      v += __shfl_xor(v, 4); v += __shfl_xor(v, 8);
      s_[mf][r] = v;
    }
  if (l15 == 0) {
#pragma unroll
    for (int mf = 0; mf < 4; ++mf)
#pragma unroll
      for (int r = 0; r < 4; ++r) lRed[(16 * mf + 4 * g + r) * 4 + w] = s_[mf][r];
  }
  __syncthreads();
  if (t < 64) lMu[t] = (lRed[t * 4] + lRed[t * 4 + 1] + lRed[t * 4 + 2] + lRed[t * 4 + 3]) * (1.f / 512.f);
  __syncthreads();

  // variance
  float mu_[4][4];
#pragma unroll
  for (int mf = 0; mf < 4; ++mf)
#pragma unroll
    for (int r = 0; r < 4; ++r) mu_[mf][r] = lMu[16 * mf + 4 * g + r];
#pragma unroll
  for (int mf = 0; mf < 4; ++mf)
#pragma unroll
    for (int r = 0; r < 4; ++r) {
      float v = 0.f;
#pragma unroll
      for (int nf = 0; nf < 8; ++nf) {
        const float d = acc[mf][nf][r] - mu_[mf][r];
        v += d * d;
      }
      v += __shfl_xor(v, 1); v += __shfl_xor(v, 2);
      v += __shfl_xor(v, 4); v += __shfl_xor(v, 8);
      s_[mf][r] = v;
    }
  if (l15 == 0) {
#pragma unroll
    for (int mf = 0; mf < 4; ++mf)
#pragma unroll
      for (int r = 0; r < 4; ++r) lRed[(16 * mf + 4 * g + r) * 4 + w] = s_[mf][r];
  }
  __syncthreads();
  if (t < 64) {
    const float sse = lRed[t * 4] + lRed[t * 4 + 1] + lRed[t * 4 + 2] + lRed[t * 4 + 3];
    lRs[t] = rsqrtf(sse * (1.f / 512.f) + 1e-5f);
  }
  __syncthreads();

  // normalize + gamma/beta + exact GELU + store (overwrites the A rows we own)
#pragma unroll
  for (int mf = 0; mf < 4; ++mf)
#pragma unroll
    for (int r = 0; r < 4; ++r) {
      const int row = 16 * mf + 4 * g + r;
      const int er = e0 + row;
      if (er >= E) continue;
      const float mu = lMu[row], rs = lRs[row];
#pragma unroll
      for (int nf = 0; nf < 8; ++nf) {
        const int col = cw + 16 * nf + l15;
        const float x = (acc[mf][nf][r] - mu) * rs * gam[nf] + bet[nf];
        const float y = 0.5f * x * (1.f + erff(x * 0.70710678118654752f));
        out[(size_t)er * 512 + col] = y;
      }
    }
}

// ---------------------------------------------------------------------------
extern "C" void kernel_launch(void* const* d_in, const int* in_sizes, int n_in,
                              void* d_out, int out_size, void* d_ws, size_t ws_size,
                              hipStream_t stream) {
  const float* z = (const float*)d_in[0];
  const float* W = (const float*)d_in[1];
  const float* bias = (const float*)d_in[2];
  const float* gamma = (const float*)d_in[3];
  const float* beta = (const float*)d_in[4];
  const int* midx = (const int*)d_in[5];
  const int* seg = (const int*)d_in[6];
  const int M = in_sizes[5];
  const int E = out_size / 512;

  char* ws = (char*)d_ws;
  size_t off = 0;
  auto alloc = [&](size_t bytes) {
    void* p = ws + off;
    off = (off + bytes + 255) & ~(size_t)255;
    return p;
  };
  int* beg = (int*)alloc((size_t)E * 4);
  int* end_ = (int*)alloc((size_t)E * 4);
  unsigned short* Whi = (unsigned short*)alloc((size_t)512 * 512 * 2);
  unsigned short* Wlo = (unsigned short*)alloc((size_t)512 * 512 * 2);
  (void)ws_size; (void)n_in;

  unsigned short* a16 = (unsigned short*)d_out;   // A-buffer aliases the output

  k_zero<<<(E + 255) / 256, 256, 0, stream>>>(beg, end_, E);
  k_bounds<<<(M + 255) / 256, 256, 0, stream>>>(seg, beg, end_, M);
  k_wsplit<<<(512 * 512 + 255) / 256, 256, 0, stream>>>(W, Whi, Wlo);
  k_mean<<<E, 128, 0, stream>>>(z, midx, beg, end_, a16);
  k_gemm<<<(E + 63) / 64, 256, 0, stream>>>(a16, Whi, Wlo, bias, gamma, beta,
                                            (float*)d_out, E);
}